// Round 13
// baseline (257.651 us; speedup 1.0000x reference)
//
#include <hip/hip_runtime.h>

typedef unsigned short ushort_t;
typedef __attribute__((ext_vector_type(8))) short short8;
typedef __attribute__((ext_vector_type(4))) float f32x4;
typedef __attribute__((ext_vector_type(4))) unsigned short ushort4_t;
typedef __attribute__((ext_vector_type(4))) unsigned int uint4_t;

// Problem constants
#define BB 2
#define SS 2048
#define EE 1024
#define HH 16
#define DD 64
#define MM (BB*SS)   // 4096

// Workspace layout (ushort element offsets)
#define QB_OFF  0u          // q bf16 [M][E]; reused as ctx bf16 [M][E] after gemm_qkv
#define KB_OFF  4194304u
#define VB_OFF  8388608u
#define WQ_OFF  12582912u   // Wq bf16 [E][E]
#define WK_OFF  13631488u
#define WV_OFF  14680064u
#define WO_OFF  15728640u
#define QH_OFF  16777216u   // Qh bf16 [B][H][S][D] (pre-scaled by 0.125*log2e)
#define KH_OFF  20971520u   // Kh bf16 [B][H][S][D]
#define VT_OFF  25165824u   // VhT bf16 [B][H][D][S'] (S k''-permuted per 128-block, R13)
#define CTX_OFF QB_OFF      // ctx aliases dead q-bf16 region
#define MB_OFF  29360128u   // maskbits u32 [B][S(q)][S/32 k-words] (natural orientation)

__device__ __forceinline__ ushort_t f2bf(float x) {
    unsigned u = __builtin_bit_cast(unsigned, x);
    u += 0x7FFFu + ((u >> 16) & 1u);
    return (ushort_t)(u >> 16);
}

// single-instruction pack: dst = {bf16(b)[hi], bf16(a)[lo]}, RNE (T12 recipe)
__device__ __forceinline__ unsigned cvt_pk_bf16(float a, float b) {
    unsigned r;
    asm("v_cvt_pk_bf16_f32 %0, %1, %2" : "=v"(r) : "v"(a), "v"(b));
    return r;
}

__device__ __forceinline__ void load_lds16(const void* g, void* l) {
    __builtin_amdgcn_global_load_lds((const __attribute__((address_space(1))) void*)g,
                                     (__attribute__((address_space(3))) void*)l, 16, 0, 0);
}

// ---------------------------------------------------------------------------
// Kernel 1: cast fp32->bf16 (q,k,v,Wq,Wk,Wv,Wo) + mask bit-pack.
// maskbits natural orientation [b][q][kw]: word kw bit t = (mask[b][0][q][kw*32+t]!=0).
// R14: 4 waves per q-row, 8 fully-unrolled ballot iterations.
// ---------------------------------------------------------------------------
__global__ __launch_bounds__(256) void prep_kernel(
    const float* __restrict__ q, const float* __restrict__ k, const float* __restrict__ v,
    const int* __restrict__ mask,
    const float* __restrict__ Wq, const float* __restrict__ Wk,
    const float* __restrict__ Wv, const float* __restrict__ Wo,
    ushort_t* __restrict__ wsb, unsigned* __restrict__ maskbits)
{
    int g = blockIdx.x;
    if (g < 16384) {
        int idx = g * 256 + threadIdx.x;  // float4 index
        const float* src; ushort_t* dst; int rel;
        if      (idx < 1048576) { src = q;  dst = wsb + QB_OFF; rel = idx; }
        else if (idx < 2097152) { src = k;  dst = wsb + KB_OFF; rel = idx - 1048576; }
        else if (idx < 3145728) { src = v;  dst = wsb + VB_OFF; rel = idx - 2097152; }
        else if (idx < 3407872) { src = Wq; dst = wsb + WQ_OFF; rel = idx - 3145728; }
        else if (idx < 3670016) { src = Wk; dst = wsb + WK_OFF; rel = idx - 3407872; }
        else if (idx < 3932160) { src = Wv; dst = wsb + WV_OFF; rel = idx - 3670016; }
        else                    { src = Wo; dst = wsb + WO_OFF; rel = idx - 3932160; }
        f32x4 val = ((const f32x4*)src)[rel];
        ushort4_t o;
        o.x = f2bf(val.x); o.y = f2bf(val.y); o.z = f2bf(val.z); o.w = f2bf(val.w);
        ((ushort4_t*)dst)[rel] = o;
    } else {
        // 4 waves per q-row, one 512-k segment each; 8 ballot iterations
        const int lane = threadIdx.x & 63;
        int wid = (g - 16384) * 4 + (threadIdx.x >> 6);   // 0..16383
        int row = wid >> 2, seg = wid & 3;
        int b = row >> 11, qr = row & 2047;
        const int* mp = mask + ((size_t)b * SS + qr) * SS + seg * 512;
        unsigned* outw = maskbits + ((size_t)b * SS + qr) * 64 + seg * 16;
        #pragma unroll
        for (int i = 0; i < 8; ++i) {
            unsigned long long bal = __ballot(mp[i * 64 + lane] != 0);
            if (lane == 0) {
                outw[i * 2]     = (unsigned)bal;
                outw[i * 2 + 1] = (unsigned)(bal >> 32);
            }
        }
    }
}

// ---------------------------------------------------------------------------
// Shared gemm_bt mainloop, BK=64 (R12): C[128x128] += A[128xK] * B^T.
// Two 32-K slabs staged per barrier-pair -> 32 MFMA between barriers.
// ---------------------------------------------------------------------------
__device__ __forceinline__ void gemm_mainloop(
    const ushort_t* __restrict__ A, const ushort_t* __restrict__ Bm,
    int m0, int n0, f32x4 acc[4][4], ushort_t* As, ushort_t* Bs)
{
    const int tid  = threadIdx.x;
    const int wave = tid >> 6, lane = tid & 63;
    const int r16  = lane >> 2;          // row within 16-row chunk
    const int c8   = (lane & 3) * 8;     // ushort col within 32-wide row
    const int lane15 = lane & 15, quad = lane >> 4;
    const int wm = wave >> 1, wn = wave & 1;

    #pragma unroll 1
    for (int kt = 0; kt < 16; ++kt) {
        const int k0 = kt * 64;
        __syncthreads();
        #pragma unroll
        for (int s = 0; s < 2; ++s) {
            const ushort_t* ga = A  + (size_t)(m0 + wave * 32 + r16) * 1024 + k0 + s * 32 + c8;
            load_lds16(ga,             As + s * 4096 + wave * 1024);
            load_lds16(ga + 16 * 1024, As + s * 4096 + wave * 1024 + 512);
            const ushort_t* gb = Bm + (size_t)(n0 + wave * 32 + r16) * 1024 + k0 + s * 32 + c8;
            load_lds16(gb,             Bs + s * 4096 + wave * 1024);
            load_lds16(gb + 16 * 1024, Bs + s * 4096 + wave * 1024 + 512);
        }
        __syncthreads();

        #pragma unroll
        for (int s = 0; s < 2; ++s) {
            short8 a[4], bf[4];
            #pragma unroll
            for (int i = 0; i < 4; ++i)
                a[i] = *(const short8*)&As[s * 4096 + (wm * 64 + i * 16 + lane15) * 32 + quad * 8];
            #pragma unroll
            for (int j = 0; j < 4; ++j)
                bf[j] = *(const short8*)&Bs[s * 4096 + (wn * 64 + j * 16 + lane15) * 32 + quad * 8];
            #pragma unroll
            for (int i = 0; i < 4; ++i)
                #pragma unroll
                for (int j = 0; j < 4; ++j)
                    acc[i][j] = __builtin_amdgcn_mfma_f32_16x16x32_bf16(a[i], bf[j], acc[i][j], 0, 0, 0);
        }
    }
}

// ---------------------------------------------------------------------------
// Kernel 2: QKV projections. R18: grid REVERTED to dim3(8,32,3) natural
// linearization (R17's XCD-grouping cut FETCH 66->37MB but regressed dur
// <56 -> 64.3us: the 8 n-blocks sharing an A-panel used to stream from 8
// XCDs in parallel (high MLP); grouping them on one XCD serialized them on
// a single L2-miss chain. Latency-bound kernel -> MLP > traffic).
// z=0: Q (scaled) -> [B,H,S,D]; z=1: K; z=2: C = Wv@v^T -> V^T k''-permuted
// (R13): k'' = 32*(kk>>5)+8*((kk>>2)&3)+4*((kk>>4)&1)+(kk&3)
// ---------------------------------------------------------------------------
__global__ __launch_bounds__(256) void gemm_qkv(
    ushort_t* __restrict__ wsb,
    const float* __restrict__ bq, const float* __restrict__ bk, const float* __restrict__ bv)
{
    __shared__ ushort_t As[2 * 4096], Bs[2 * 4096];   // 32 KB total
    const int z = blockIdx.z;
    const ushort_t* A;
    const ushort_t* Bm;
    if      (z == 0) { A = wsb + QB_OFF; Bm = wsb + WQ_OFF; }
    else if (z == 1) { A = wsb + KB_OFF; Bm = wsb + WK_OFF; }
    else             { A = wsb + WV_OFF; Bm = wsb + VB_OFF; }
    const float* bias  = (z == 0) ? bq : (z == 1) ? bk : bv;
    ushort_t* dst      = wsb + (z == 0 ? QH_OFF : z == 1 ? KH_OFF : VT_OFF);
    // z<2: m-tiles over tokens (y), n-tiles over E (x). z=2: m over E (x), n over tokens (y).
    const int m0 = (z < 2) ? blockIdx.y * 128 : blockIdx.x * 128;
    const int n0 = (z < 2) ? blockIdx.x * 128 : blockIdx.y * 128;

    f32x4 acc[4][4];
    #pragma unroll
    for (int i = 0; i < 4; ++i)
        #pragma unroll
        for (int j = 0; j < 4; ++j) acc[i][j] = (f32x4){0.f, 0.f, 0.f, 0.f};

    gemm_mainloop(A, Bm, m0, n0, acc, As, Bs);

    const int tid = threadIdx.x, wave = tid >> 6, lane = tid & 63;
    const int lane15 = lane & 15, quad = lane >> 4;
    const int wm = wave >> 1, wn = wave & 1;
    const float scale = (z == 0) ? 0.180336880111f : 1.0f;  // 1/sqrt(64) * log2(e)

    if (z < 2) {
        #pragma unroll
        for (int i = 0; i < 4; ++i) {
            #pragma unroll
            for (int j = 0; j < 4; ++j) {
                int col = n0 + wn * 64 + j * 16 + lane15;
                float bv_ = bias[col];
                int hh = col >> 6, d = col & 63;
                #pragma unroll
                for (int r2 = 0; r2 < 4; ++r2) {
                    int row = m0 + wm * 64 + i * 16 + quad * 4 + r2;
                    int bb = row >> 11, s = row & 2047;
                    float val = (acc[i][j][r2] + bv_) * scale;
                    dst[(((size_t)bb * HH + hh) * SS + s) * DD + d] = f2bf(val);
                }
            }
        }
    } else {
        // C[e][token]: row = e (hh,d), col = token; store V^T k''-permuted
        #pragma unroll
        for (int i = 0; i < 4; ++i) {
            #pragma unroll
            for (int r2 = 0; r2 < 4; ++r2) {
                int row = m0 + wm * 64 + i * 16 + quad * 4 + r2;   // e
                float bv_ = bias[row];
                int hh = row >> 6, d = row & 63;
                #pragma unroll
                for (int j = 0; j < 4; ++j) {
                    int col = n0 + wn * 64 + j * 16 + lane15;     // token
                    int bb = col >> 11, s = col & 2047;
                    int kk = s & 127;
                    // k'' = 32*(kk>>5) + 8*((kk>>2)&3) + 4*((kk>>4)&1) + (kk&3)
                    int sp = (kk & 0x60) | ((kk & 12) << 1) | ((kk & 16) >> 2) | (kk & 3);
                    dst[(((size_t)bb * HH + hh) * DD + d) * SS + (s & ~127) + sp]
                        = f2bf(acc[i][j][r2] + bv_);
                }
            }
        }
    }
}

// ---------------------------------------------------------------------------
// Kernel 3: flash attention, fixed-max softmax. R15 body (single-buffer,
// register-P via swapped QK^T, cvt_pk) + R17 XCD swizzle (kept: attn is
// KV-stream-reuse-bound across q-tiles -- 16 q-tiles of one bh share the
// same 1MB KV stream; same-XCD grouping makes the per-kt staging drain hit
// L2 (~200cyc) instead of HBM (~900cyc); attn left the top-5 after R17).
// ---------------------------------------------------------------------------
__global__ __launch_bounds__(256, 2) void attn_kernel(
    const ushort_t* __restrict__ wsb, const unsigned* __restrict__ maskbits,
    ushort_t* __restrict__ ctx)
{
    __shared__ ushort_t Ks[128 * 64];     // 16 KB
    __shared__ ushort_t Vts[64 * 128];    // 16 KB

    const int tid  = threadIdx.x;
    const int wave = tid >> 6, lane = tid & 63;
    const int lane15 = lane & 15, quad = lane >> 4;
    const int sw7 = lane15 & 7;           // swizzle key for fragment reads
    // XCD decode: xcd = bid%8 owns bh in {4*xcd..4*xcd+3}, all 16 q-tiles
    const int bid = blockIdx.x;
    const int xcd = bid & 7, t = bid >> 3;
    const int bh  = xcd * 4 + (t & 3);    // b*16 + h
    const int q0  = (t >> 2) * 128;
    const int b   = bh >> 4, h = bh & 15;

    const ushort_t* Qh  = wsb + QH_OFF;
    const ushort_t* Kh  = wsb + KH_OFF;
    const ushort_t* VhT = wsb + VT_OFF;

    // Q fragments (loop-invariant); wave owns rows q0+wave*32..+32
    short8 qfrag[2][2];
    #pragma unroll
    for (int i = 0; i < 2; ++i)
        #pragma unroll
        for (int ks = 0; ks < 2; ++ks)
            qfrag[i][ks] = *(const short8*)(Qh +
                ((size_t)bh * SS + q0 + wave * 32 + i * 16 + lane15) * DD + ks * 32 + quad * 8);

    // ones B-fragment for MFMA row-sum: B[k][n] = (n==0) ? 1 : 0
    short8 ones_frag;
    {
        short onev = (lane15 == 0) ? (short)0x3F80 : (short)0;
        #pragma unroll
        for (int e = 0; e < 8; ++e) ones_frag[e] = onev;
    }

    const f32x4 zero4 = (f32x4){0.f, 0.f, 0.f, 0.f};
    f32x4 s_acc[2][8];
    f32x4 o_acc[2][4];
    f32x4 osum[2];
    #pragma unroll
    for (int i = 0; i < 2; ++i) {
        #pragma unroll
        for (int jd = 0; jd < 4; ++jd) o_acc[i][jd] = zero4;
        osum[i] = zero4;
    }

    #pragma unroll 1
    for (int kt = 0; kt < 16; ++kt) {
        const int k0 = kt * 128;
        __syncthreads();  // prev QK done with Ks, prev PV done with Vts

        // stage K tile [128 sk][8 chunks] with swizzled global gather
        const ushort_t* Kbase = Kh + ((size_t)bh * SS + k0) * DD;
        #pragma unroll
        for (int cc = 0; cc < 4; ++cc) {
            int n = (wave * 4 + cc) * 64 + lane;       // LDS chunk id
            int row = n >> 3;
            int c = (n & 7) ^ (row & 7);               // logical chunk
            load_lds16(Kbase + row * 64 + c * 8, Ks + (wave * 4 + cc) * 512);
        }
        // stage Vt tile [64 d][16 chunks] (global is k''-permuted already)
        const ushort_t* Vbase = VhT + ((size_t)bh * DD) * SS + k0;
        #pragma unroll
        for (int cc = 0; cc < 4; ++cc) {
            int n = (wave * 4 + cc) * 64 + lane;
            int d = n >> 4;
            int c = (n & 15) ^ (d & 7);
            load_lds16(Vbase + (size_t)d * SS + c * 8, Vts + (wave * 4 + cc) * 512);
        }

        // mask words: lane's q row(s) = q0+wave*32+i*16+lane15; 4 k-words per kt
        unsigned mw2[2][4];
        {
            const int kw0 = k0 >> 5;
            #pragma unroll
            for (int i = 0; i < 2; ++i) {
                const size_t qrow = (size_t)b * SS + q0 + wave * 32 + i * 16 + lane15;
                #pragma unroll
                for (int w = 0; w < 4; ++w)
                    mw2[i][w] = maskbits[qrow * 64 + kw0 + w];
            }
        }
        __syncthreads();  // staging visible (vmcnt drains at barrier)

        // S^T = K Q^T (swapped args; scale+log2e folded into Q)
        #pragma unroll
        for (int j = 0; j < 8; ++j) {
            short8 kf = *(const short8*)&Ks[(j * 16 + lane15) * 64 + ((quad ^ sw7) << 3)];
            s_acc[0][j] = __builtin_amdgcn_mfma_f32_16x16x32_bf16(kf, qfrag[0][0], zero4, 0, 0, 0);
            s_acc[1][j] = __builtin_amdgcn_mfma_f32_16x16x32_bf16(kf, qfrag[1][0], zero4, 0, 0, 0);
        }
        #pragma unroll
        for (int j = 0; j < 8; ++j) {
            short8 kf = *(const short8*)&Ks[(j * 16 + lane15) * 64 + (((4 + quad) ^ sw7) << 3)];
            s_acc[0][j] = __builtin_amdgcn_mfma_f32_16x16x32_bf16(kf, qfrag[0][1], s_acc[0][j], 0, 0, 0);
            s_acc[1][j] = __builtin_amdgcn_mfma_f32_16x16x32_bf16(kf, qfrag[1][1], s_acc[1][j], 0, 0, 0);
        }
        // lane now holds S[q = wave*32+i*16+lane15][k = k0 + j*16 + quad*4 + r]

        // softmax + PV fully in registers: 4 slices of 32 k''
        #pragma unroll
        for (int ks = 0; ks < 4; ++ks) {
            short8 ap[2];
            #pragma unroll
            for (int i = 0; i < 2; ++i) {
                // j = 2*ks + hf ; mask word = mw2[i][ks], bit = hf*16+quad*4+r
                float p[2][4];
                #pragma unroll
                for (int hf = 0; hf < 2; ++hf) {
                    #pragma unroll
                    for (int r = 0; r < 4; ++r) {
                        float e = __builtin_amdgcn_exp2f(s_acc[i][ks * 2 + hf][r]);
                        p[hf][r] = ((mw2[i][ks] >> (hf * 16 + quad * 4 + r)) & 1u) ? e : 0.f;
                    }
                }
                uint4_t api;
                api.x = cvt_pk_bf16(p[0][0], p[0][1]);
                api.y = cvt_pk_bf16(p[0][2], p[0][3]);
                api.z = cvt_pk_bf16(p[1][0], p[1][1]);
                api.w = cvt_pk_bf16(p[1][2], p[1][3]);
                ap[i] = __builtin_bit_cast(short8, api);
            }
            #pragma unroll
            for (int jd = 0; jd < 4; ++jd) {
                short8 bv_ = *(const short8*)&Vts[(jd * 16 + lane15) * 128 +
                                                  (((ks * 4 + quad) ^ sw7) << 3)];
                o_acc[0][jd] = __builtin_amdgcn_mfma_f32_16x16x32_bf16(ap[0], bv_, o_acc[0][jd], 0, 0, 0);
                o_acc[1][jd] = __builtin_amdgcn_mfma_f32_16x16x32_bf16(ap[1], bv_, o_acc[1][jd], 0, 0, 0);
            }
            osum[0] = __builtin_amdgcn_mfma_f32_16x16x32_bf16(ap[0], ones_frag, osum[0], 0, 0, 0);
            osum[1] = __builtin_amdgcn_mfma_f32_16x16x32_bf16(ap[1], ones_frag, osum[1], 0, 0, 0);
        }
    }

    // epilogue: l sits in col-0 lanes (lane15==0) of osum; broadcast within quad group
    #pragma unroll
    for (int i = 0; i < 2; ++i) {
        #pragma unroll
        for (int r = 0; r < 4; ++r) {
            float l = __shfl(osum[i][r], lane & 48);   // src = quad*16 (lane15==0)
            float inv = 1.0f / l;
            int row = q0 + wave * 32 + i * 16 + quad * 4 + r;
            #pragma unroll
            for (int jd = 0; jd < 4; ++jd) {
                int col = h * DD + jd * 16 + lane15;
                ctx[((size_t)b * SS + row) * EE + col] = f2bf(o_acc[i][jd][r] * inv);
            }
        }
    }
}

// ---------------------------------------------------------------------------
// Kernel 4: out = ctx @ Wo^T + bo (fp32). 64x128 tiles, BK=128 (R15).
// R17 XCD swizzle kept (ctx m-tile grouped per XCD; gemm_out left the top-5).
// ---------------------------------------------------------------------------
__global__ __launch_bounds__(256) void gemm_out(
    const ushort_t* __restrict__ wsb, const float* __restrict__ bo, float* __restrict__ out)
{
    __shared__ ushort_t As[4 * 2048];   // 4 slabs x 64 rows x 32 cols
    __shared__ ushort_t Bs[4 * 4096];   // 4 slabs x 128 rows x 32 cols
    const ushort_t* A  = wsb + CTX_OFF;
    const ushort_t* Bm = wsb + WO_OFF;
    const int bid = blockIdx.x;          // 0..511
    const int xs = bid & 7, t = bid >> 3;   // t 0..63
    const int m0 = (xs * 8 + (t & 7)) * 64; // 64 m-tiles, grouped per XCD
    const int n0 = (t >> 3) * 128;          // 8 n-tiles

    const int tid = threadIdx.x, wave = tid >> 6, lane = tid & 63;
    const int lane15 = lane & 15, quad = lane >> 4;

    f32x4 acc[8];
    #pragma unroll
    for (int j = 0; j < 8; ++j) acc[j] = (f32x4){0.f, 0.f, 0.f, 0.f};

    #pragma unroll 1
    for (int kt = 0; kt < 8; ++kt) {
        const int k0 = kt * 128;
        __syncthreads();
        #pragma unroll
        for (int s = 0; s < 4; ++s) {
            {
                int n = wave * 64 + lane;              // A chunk 0..255 (4 chunks/row)
                load_lds16(A + (size_t)(m0 + (n >> 2)) * 1024 + k0 + s * 32 + (n & 3) * 8,
                           As + s * 2048 + wave * 512);
            }
            #pragma unroll
            for (int m = 0; m < 2; ++m) {
                int n = m * 256 + wave * 64 + lane;    // B chunk 0..511
                load_lds16(Bm + (size_t)(n0 + (n >> 2)) * 1024 + k0 + s * 32 + (n & 3) * 8,
                           Bs + s * 4096 + (m * 256 + wave * 64) * 8);
            }
        }
        __syncthreads();

        #pragma unroll
        for (int s = 0; s < 4; ++s) {
            short8 a = *(const short8*)&As[s * 2048 + (wave * 16 + lane15) * 32 + quad * 8];
            #pragma unroll
            for (int j = 0; j < 8; ++j) {
                short8 bf = *(const short8*)&Bs[s * 4096 + (j * 16 + lane15) * 32 + quad * 8];
                acc[j] = __builtin_amdgcn_mfma_f32_16x16x32_bf16(a, bf, acc[j], 0, 0, 0);
            }
        }
    }

    #pragma unroll
    for (int j = 0; j < 8; ++j) {
        int col = n0 + j * 16 + lane15;
        float bv_ = bo[col];
        #pragma unroll
        for (int r = 0; r < 4; ++r) {
            int row = m0 + wave * 16 + quad * 4 + r;
            out[(size_t)row * EE + col] = acc[j][r] + bv_;
        }
    }
}

// ---------------------------------------------------------------------------
extern "C" void kernel_launch(void* const* d_in, const int* in_sizes, int n_in,
                              void* d_out, int out_size, void* d_ws, size_t ws_size,
                              hipStream_t stream) {
    const float* q    = (const float*)d_in[0];
    const float* k    = (const float*)d_in[1];
    const float* v    = (const float*)d_in[2];
    const int*   mask = (const int*)  d_in[3];
    const float* Wq   = (const float*)d_in[4];
    const float* bq   = (const float*)d_in[5];
    const float* Wk   = (const float*)d_in[6];
    const float* bk   = (const float*)d_in[7];
    const float* Wv   = (const float*)d_in[8];
    const float* bv   = (const float*)d_in[9];
    const float* Wo   = (const float*)d_in[10];
    const float* bo   = (const float*)d_in[11];

    ushort_t* wsb = (ushort_t*)d_ws;
    unsigned* maskbits = (unsigned*)(wsb + MB_OFF);

    prep_kernel<<<20480, 256, 0, stream>>>(q, k, v, mask, Wq, Wk, Wv, Wo, wsb, maskbits);
    gemm_qkv<<<dim3(8, 32, 3), 256, 0, stream>>>(wsb, bq, bk, bv);
    attn_kernel<<<512, 256, 0, stream>>>(wsb, maskbits, wsb + CTX_OFF);
    gemm_out<<<512, 256, 0, stream>>>(wsb, bo, (float*)d_out);
}

// Round 14
// 256.386 us; speedup vs baseline: 1.0049x; 1.0049x over previous
//
#include <hip/hip_runtime.h>

typedef unsigned short ushort_t;
typedef __attribute__((ext_vector_type(8))) short short8;
typedef __attribute__((ext_vector_type(4))) float f32x4;
typedef __attribute__((ext_vector_type(4))) unsigned short ushort4_t;
typedef __attribute__((ext_vector_type(4))) unsigned int uint4_t;

// Problem constants
#define BB 2
#define SS 2048
#define EE 1024
#define HH 16
#define DD 64
#define MM (BB*SS)   // 4096

// Workspace layout (ushort element offsets)
#define QB_OFF  0u          // q bf16 [M][E]; reused as ctx bf16 [M][E] after gemm_qkv
#define KB_OFF  4194304u
#define VB_OFF  8388608u
#define WQ_OFF  12582912u   // Wq bf16 [E][E]
#define WK_OFF  13631488u
#define WV_OFF  14680064u
#define WO_OFF  15728640u
#define QH_OFF  16777216u   // Qh bf16 [B][H][S][D] (pre-scaled by 0.125*log2e)
#define KH_OFF  20971520u   // Kh bf16 [B][H][S][D]
#define VT_OFF  25165824u   // VhT bf16 [B][H][D][S'] (S k''-permuted per 128-block, R13)
#define CTX_OFF QB_OFF      // ctx aliases dead q-bf16 region
#define MB_OFF  29360128u   // maskbits u32 [B][S(q)][S/32 k-words] (natural orientation)

__device__ __forceinline__ ushort_t f2bf(float x) {
    unsigned u = __builtin_bit_cast(unsigned, x);
    u += 0x7FFFu + ((u >> 16) & 1u);
    return (ushort_t)(u >> 16);
}

// single-instruction pack: dst = {bf16(b)[hi], bf16(a)[lo]}, RNE (T12 recipe)
__device__ __forceinline__ unsigned cvt_pk_bf16(float a, float b) {
    unsigned r;
    asm("v_cvt_pk_bf16_f32 %0, %1, %2" : "=v"(r) : "v"(a), "v"(b));
    return r;
}

__device__ __forceinline__ void load_lds16(const void* g, void* l) {
    __builtin_amdgcn_global_load_lds((const __attribute__((address_space(1))) void*)g,
                                     (__attribute__((address_space(3))) void*)l, 16, 0, 0);
}

// ---------------------------------------------------------------------------
// Kernel 1: cast fp32->bf16 (q,k,v,Wq,Wk,Wv,Wo) + mask bit-pack.
// maskbits natural orientation [b][q][kw]: word kw bit t = (mask[b][0][q][kw*32+t]!=0).
// R14: 4 waves per q-row, 8 fully-unrolled ballot iterations.
// ---------------------------------------------------------------------------
__global__ __launch_bounds__(256) void prep_kernel(
    const float* __restrict__ q, const float* __restrict__ k, const float* __restrict__ v,
    const int* __restrict__ mask,
    const float* __restrict__ Wq, const float* __restrict__ Wk,
    const float* __restrict__ Wv, const float* __restrict__ Wo,
    ushort_t* __restrict__ wsb, unsigned* __restrict__ maskbits)
{
    int g = blockIdx.x;
    if (g < 16384) {
        int idx = g * 256 + threadIdx.x;  // float4 index
        const float* src; ushort_t* dst; int rel;
        if      (idx < 1048576) { src = q;  dst = wsb + QB_OFF; rel = idx; }
        else if (idx < 2097152) { src = k;  dst = wsb + KB_OFF; rel = idx - 1048576; }
        else if (idx < 3145728) { src = v;  dst = wsb + VB_OFF; rel = idx - 2097152; }
        else if (idx < 3407872) { src = Wq; dst = wsb + WQ_OFF; rel = idx - 3145728; }
        else if (idx < 3670016) { src = Wk; dst = wsb + WK_OFF; rel = idx - 3407872; }
        else if (idx < 3932160) { src = Wv; dst = wsb + WV_OFF; rel = idx - 3670016; }
        else                    { src = Wo; dst = wsb + WO_OFF; rel = idx - 3932160; }
        f32x4 val = ((const f32x4*)src)[rel];
        ushort4_t o;
        o.x = f2bf(val.x); o.y = f2bf(val.y); o.z = f2bf(val.z); o.w = f2bf(val.w);
        ((ushort4_t*)dst)[rel] = o;
    } else {
        // 4 waves per q-row, one 512-k segment each; 8 ballot iterations
        const int lane = threadIdx.x & 63;
        int wid = (g - 16384) * 4 + (threadIdx.x >> 6);   // 0..16383
        int row = wid >> 2, seg = wid & 3;
        int b = row >> 11, qr = row & 2047;
        const int* mp = mask + ((size_t)b * SS + qr) * SS + seg * 512;
        unsigned* outw = maskbits + ((size_t)b * SS + qr) * 64 + seg * 16;
        #pragma unroll
        for (int i = 0; i < 8; ++i) {
            unsigned long long bal = __ballot(mp[i * 64 + lane] != 0);
            if (lane == 0) {
                outw[i * 2]     = (unsigned)bal;
                outw[i * 2 + 1] = (unsigned)(bal >> 32);
            }
        }
    }
}

// ---------------------------------------------------------------------------
// Shared gemm_bt mainloop, BK=64 (R12): C[128x128] += A[128xK] * B^T.
// R19: T2 XOR-swizzle on As/Bs (rows are 64B = 16 banks -> unswizzled b128
// fragment reads were 8-way bank conflicts, SQ_LDS_BANK_CONFLICT 3.1M, cost
// ~2.94x). Chunk (16B) index XORed with (row>>1)&3; key derivation: bank
// group = f(row&1, chunk') -> (row>>1)&3 spreads 16 rows over all 8 groups,
// residual 2-way = free (m136). global_load_lds writes linearly, so the
// permutation is applied on the GLOBAL source column (same 64B row segment,
// coalescing intact) and inverted on the read (both-sides, rule #21).
// ---------------------------------------------------------------------------
__device__ __forceinline__ void gemm_mainloop(
    const ushort_t* __restrict__ A, const ushort_t* __restrict__ Bm,
    int m0, int n0, f32x4 acc[4][4], ushort_t* As, ushort_t* Bs)
{
    const int tid  = threadIdx.x;
    const int wave = tid >> 6, lane = tid & 63;
    const int r16  = lane >> 2;          // row within 16-row chunk
    const int csw  = (((lane & 3) ^ ((r16 >> 1) & 3)) * 8);  // swizzled src chunk col
    const int lane15 = lane & 15, quad = lane >> 4;
    const int rsw  = ((quad ^ ((lane15 >> 1) & 3)) << 3);    // swizzled read chunk col
    const int wm = wave >> 1, wn = wave & 1;

    #pragma unroll 1
    for (int kt = 0; kt < 16; ++kt) {
        const int k0 = kt * 64;
        __syncthreads();
        #pragma unroll
        for (int s = 0; s < 2; ++s) {
            const ushort_t* ga = A  + (size_t)(m0 + wave * 32 + r16) * 1024 + k0 + s * 32 + csw;
            load_lds16(ga,             As + s * 4096 + wave * 1024);
            load_lds16(ga + 16 * 1024, As + s * 4096 + wave * 1024 + 512);
            const ushort_t* gb = Bm + (size_t)(n0 + wave * 32 + r16) * 1024 + k0 + s * 32 + csw;
            load_lds16(gb,             Bs + s * 4096 + wave * 1024);
            load_lds16(gb + 16 * 1024, Bs + s * 4096 + wave * 1024 + 512);
        }
        __syncthreads();

        #pragma unroll
        for (int s = 0; s < 2; ++s) {
            short8 a[4], bf[4];
            #pragma unroll
            for (int i = 0; i < 4; ++i)
                a[i] = *(const short8*)&As[s * 4096 + (wm * 64 + i * 16 + lane15) * 32 + rsw];
            #pragma unroll
            for (int j = 0; j < 4; ++j)
                bf[j] = *(const short8*)&Bs[s * 4096 + (wn * 64 + j * 16 + lane15) * 32 + rsw];
            #pragma unroll
            for (int i = 0; i < 4; ++i)
                #pragma unroll
                for (int j = 0; j < 4; ++j)
                    acc[i][j] = __builtin_amdgcn_mfma_f32_16x16x32_bf16(a[i], bf[j], acc[i][j], 0, 0, 0);
        }
    }
}

// ---------------------------------------------------------------------------
// Kernel 2: QKV projections. Grid dim3(8,32,3) natural linearization (R18;
// the 8 n-blocks sharing an A-panel stream from 8 XCDs in parallel -- MLP >
// traffic for this latency-bound kernel; R17's XCD-grouping regressed).
// z=0: Q (scaled) -> [B,H,S,D]; z=1: K; z=2: C = Wv@v^T -> V^T k''-permuted
// (R13): k'' = 32*(kk>>5)+8*((kk>>2)&3)+4*((kk>>4)&1)+(kk&3)
// ---------------------------------------------------------------------------
__global__ __launch_bounds__(256) void gemm_qkv(
    ushort_t* __restrict__ wsb,
    const float* __restrict__ bq, const float* __restrict__ bk, const float* __restrict__ bv)
{
    __shared__ ushort_t As[2 * 4096], Bs[2 * 4096];   // 32 KB total
    const int z = blockIdx.z;
    const ushort_t* A;
    const ushort_t* Bm;
    if      (z == 0) { A = wsb + QB_OFF; Bm = wsb + WQ_OFF; }
    else if (z == 1) { A = wsb + KB_OFF; Bm = wsb + WK_OFF; }
    else             { A = wsb + WV_OFF; Bm = wsb + VB_OFF; }
    const float* bias  = (z == 0) ? bq : (z == 1) ? bk : bv;
    ushort_t* dst      = wsb + (z == 0 ? QH_OFF : z == 1 ? KH_OFF : VT_OFF);
    // z<2: m-tiles over tokens (y), n-tiles over E (x). z=2: m over E (x), n over tokens (y).
    const int m0 = (z < 2) ? blockIdx.y * 128 : blockIdx.x * 128;
    const int n0 = (z < 2) ? blockIdx.x * 128 : blockIdx.y * 128;

    f32x4 acc[4][4];
    #pragma unroll
    for (int i = 0; i < 4; ++i)
        #pragma unroll
        for (int j = 0; j < 4; ++j) acc[i][j] = (f32x4){0.f, 0.f, 0.f, 0.f};

    gemm_mainloop(A, Bm, m0, n0, acc, As, Bs);

    const int tid = threadIdx.x, wave = tid >> 6, lane = tid & 63;
    const int lane15 = lane & 15, quad = lane >> 4;
    const int wm = wave >> 1, wn = wave & 1;
    const float scale = (z == 0) ? 0.180336880111f : 1.0f;  // 1/sqrt(64) * log2(e)

    if (z < 2) {
        #pragma unroll
        for (int i = 0; i < 4; ++i) {
            #pragma unroll
            for (int j = 0; j < 4; ++j) {
                int col = n0 + wn * 64 + j * 16 + lane15;
                float bv_ = bias[col];
                int hh = col >> 6, d = col & 63;
                #pragma unroll
                for (int r2 = 0; r2 < 4; ++r2) {
                    int row = m0 + wm * 64 + i * 16 + quad * 4 + r2;
                    int bb = row >> 11, s = row & 2047;
                    float val = (acc[i][j][r2] + bv_) * scale;
                    dst[(((size_t)bb * HH + hh) * SS + s) * DD + d] = f2bf(val);
                }
            }
        }
    } else {
        // C[e][token]: row = e (hh,d), col = token; store V^T k''-permuted
        #pragma unroll
        for (int i = 0; i < 4; ++i) {
            #pragma unroll
            for (int r2 = 0; r2 < 4; ++r2) {
                int row = m0 + wm * 64 + i * 16 + quad * 4 + r2;   // e
                float bv_ = bias[row];
                int hh = row >> 6, d = row & 63;
                #pragma unroll
                for (int j = 0; j < 4; ++j) {
                    int col = n0 + wn * 64 + j * 16 + lane15;     // token
                    int bb = col >> 11, s = col & 2047;
                    int kk = s & 127;
                    // k'' = 32*(kk>>5) + 8*((kk>>2)&3) + 4*((kk>>4)&1) + (kk&3)
                    int sp = (kk & 0x60) | ((kk & 12) << 1) | ((kk & 16) >> 2) | (kk & 3);
                    dst[(((size_t)bb * HH + hh) * DD + d) * SS + (s & ~127) + sp]
                        = f2bf(acc[i][j][r2] + bv_);
                }
            }
        }
    }
}

// ---------------------------------------------------------------------------
// Kernel 3: flash attention, fixed-max softmax. R15 body (single-buffer,
// register-P via swapped QK^T, cvt_pk) + R17 XCD swizzle (16 q-tiles of one
// bh share its 1MB KV stream on one XCD -> staging drains hit L2 not HBM).
// UNCHANGED from R18.
// ---------------------------------------------------------------------------
__global__ __launch_bounds__(256, 2) void attn_kernel(
    const ushort_t* __restrict__ wsb, const unsigned* __restrict__ maskbits,
    ushort_t* __restrict__ ctx)
{
    __shared__ ushort_t Ks[128 * 64];     // 16 KB
    __shared__ ushort_t Vts[64 * 128];    // 16 KB

    const int tid  = threadIdx.x;
    const int wave = tid >> 6, lane = tid & 63;
    const int lane15 = lane & 15, quad = lane >> 4;
    const int sw7 = lane15 & 7;           // swizzle key for fragment reads
    // XCD decode: xcd = bid%8 owns bh in {4*xcd..4*xcd+3}, all 16 q-tiles
    const int bid = blockIdx.x;
    const int xcd = bid & 7, t = bid >> 3;
    const int bh  = xcd * 4 + (t & 3);    // b*16 + h
    const int q0  = (t >> 2) * 128;
    const int b   = bh >> 4, h = bh & 15;

    const ushort_t* Qh  = wsb + QH_OFF;
    const ushort_t* Kh  = wsb + KH_OFF;
    const ushort_t* VhT = wsb + VT_OFF;

    // Q fragments (loop-invariant); wave owns rows q0+wave*32..+32
    short8 qfrag[2][2];
    #pragma unroll
    for (int i = 0; i < 2; ++i)
        #pragma unroll
        for (int ks = 0; ks < 2; ++ks)
            qfrag[i][ks] = *(const short8*)(Qh +
                ((size_t)bh * SS + q0 + wave * 32 + i * 16 + lane15) * DD + ks * 32 + quad * 8);

    // ones B-fragment for MFMA row-sum: B[k][n] = (n==0) ? 1 : 0
    short8 ones_frag;
    {
        short onev = (lane15 == 0) ? (short)0x3F80 : (short)0;
        #pragma unroll
        for (int e = 0; e < 8; ++e) ones_frag[e] = onev;
    }

    const f32x4 zero4 = (f32x4){0.f, 0.f, 0.f, 0.f};
    f32x4 s_acc[2][8];
    f32x4 o_acc[2][4];
    f32x4 osum[2];
    #pragma unroll
    for (int i = 0; i < 2; ++i) {
        #pragma unroll
        for (int jd = 0; jd < 4; ++jd) o_acc[i][jd] = zero4;
        osum[i] = zero4;
    }

    #pragma unroll 1
    for (int kt = 0; kt < 16; ++kt) {
        const int k0 = kt * 128;
        __syncthreads();  // prev QK done with Ks, prev PV done with Vts

        // stage K tile [128 sk][8 chunks] with swizzled global gather
        const ushort_t* Kbase = Kh + ((size_t)bh * SS + k0) * DD;
        #pragma unroll
        for (int cc = 0; cc < 4; ++cc) {
            int n = (wave * 4 + cc) * 64 + lane;       // LDS chunk id
            int row = n >> 3;
            int c = (n & 7) ^ (row & 7);               // logical chunk
            load_lds16(Kbase + row * 64 + c * 8, Ks + (wave * 4 + cc) * 512);
        }
        // stage Vt tile [64 d][16 chunks] (global is k''-permuted already)
        const ushort_t* Vbase = VhT + ((size_t)bh * DD) * SS + k0;
        #pragma unroll
        for (int cc = 0; cc < 4; ++cc) {
            int n = (wave * 4 + cc) * 64 + lane;
            int d = n >> 4;
            int c = (n & 15) ^ (d & 7);
            load_lds16(Vbase + (size_t)d * SS + c * 8, Vts + (wave * 4 + cc) * 512);
        }

        // mask words: lane's q row(s) = q0+wave*32+i*16+lane15; 4 k-words per kt
        unsigned mw2[2][4];
        {
            const int kw0 = k0 >> 5;
            #pragma unroll
            for (int i = 0; i < 2; ++i) {
                const size_t qrow = (size_t)b * SS + q0 + wave * 32 + i * 16 + lane15;
                #pragma unroll
                for (int w = 0; w < 4; ++w)
                    mw2[i][w] = maskbits[qrow * 64 + kw0 + w];
            }
        }
        __syncthreads();  // staging visible (vmcnt drains at barrier)

        // S^T = K Q^T (swapped args; scale+log2e folded into Q)
        #pragma unroll
        for (int j = 0; j < 8; ++j) {
            short8 kf = *(const short8*)&Ks[(j * 16 + lane15) * 64 + ((quad ^ sw7) << 3)];
            s_acc[0][j] = __builtin_amdgcn_mfma_f32_16x16x32_bf16(kf, qfrag[0][0], zero4, 0, 0, 0);
            s_acc[1][j] = __builtin_amdgcn_mfma_f32_16x16x32_bf16(kf, qfrag[1][0], zero4, 0, 0, 0);
        }
        #pragma unroll
        for (int j = 0; j < 8; ++j) {
            short8 kf = *(const short8*)&Ks[(j * 16 + lane15) * 64 + (((4 + quad) ^ sw7) << 3)];
            s_acc[0][j] = __builtin_amdgcn_mfma_f32_16x16x32_bf16(kf, qfrag[0][1], s_acc[0][j], 0, 0, 0);
            s_acc[1][j] = __builtin_amdgcn_mfma_f32_16x16x32_bf16(kf, qfrag[1][1], s_acc[1][j], 0, 0, 0);
        }
        // lane now holds S[q = wave*32+i*16+lane15][k = k0 + j*16 + quad*4 + r]

        // softmax + PV fully in registers: 4 slices of 32 k''
        #pragma unroll
        for (int ks = 0; ks < 4; ++ks) {
            short8 ap[2];
            #pragma unroll
            for (int i = 0; i < 2; ++i) {
                // j = 2*ks + hf ; mask word = mw2[i][ks], bit = hf*16+quad*4+r
                float p[2][4];
                #pragma unroll
                for (int hf = 0; hf < 2; ++hf) {
                    #pragma unroll
                    for (int r = 0; r < 4; ++r) {
                        float e = __builtin_amdgcn_exp2f(s_acc[i][ks * 2 + hf][r]);
                        p[hf][r] = ((mw2[i][ks] >> (hf * 16 + quad * 4 + r)) & 1u) ? e : 0.f;
                    }
                }
                uint4_t api;
                api.x = cvt_pk_bf16(p[0][0], p[0][1]);
                api.y = cvt_pk_bf16(p[0][2], p[0][3]);
                api.z = cvt_pk_bf16(p[1][0], p[1][1]);
                api.w = cvt_pk_bf16(p[1][2], p[1][3]);
                ap[i] = __builtin_bit_cast(short8, api);
            }
            #pragma unroll
            for (int jd = 0; jd < 4; ++jd) {
                short8 bv_ = *(const short8*)&Vts[(jd * 16 + lane15) * 128 +
                                                  (((ks * 4 + quad) ^ sw7) << 3)];
                o_acc[0][jd] = __builtin_amdgcn_mfma_f32_16x16x32_bf16(ap[0], bv_, o_acc[0][jd], 0, 0, 0);
                o_acc[1][jd] = __builtin_amdgcn_mfma_f32_16x16x32_bf16(ap[1], bv_, o_acc[1][jd], 0, 0, 0);
            }
            osum[0] = __builtin_amdgcn_mfma_f32_16x16x32_bf16(ap[0], ones_frag, osum[0], 0, 0, 0);
            osum[1] = __builtin_amdgcn_mfma_f32_16x16x32_bf16(ap[1], ones_frag, osum[1], 0, 0, 0);
        }
    }

    // epilogue: l sits in col-0 lanes (lane15==0) of osum; broadcast within quad group
    #pragma unroll
    for (int i = 0; i < 2; ++i) {
        #pragma unroll
        for (int r = 0; r < 4; ++r) {
            float l = __shfl(osum[i][r], lane & 48);   // src = quad*16 (lane15==0)
            float inv = 1.0f / l;
            int row = q0 + wave * 32 + i * 16 + quad * 4 + r;
            #pragma unroll
            for (int jd = 0; jd < 4; ++jd) {
                int col = h * DD + jd * 16 + lane15;
                ctx[((size_t)b * SS + row) * EE + col] = f2bf(o_acc[i][jd][r] * inv);
            }
        }
    }
}

// ---------------------------------------------------------------------------
// Kernel 4: out = ctx @ Wo^T + bo (fp32). 64x128 tiles, BK=128 (R15), R17
// XCD swizzle. R19: same T2 XOR-swizzle as gemm_mainloop on As/Bs (rows are
// 64B; unswizzled b128 reads were 8-way conflicts).
// ---------------------------------------------------------------------------
__global__ __launch_bounds__(256) void gemm_out(
    const ushort_t* __restrict__ wsb, const float* __restrict__ bo, float* __restrict__ out)
{
    __shared__ ushort_t As[4 * 2048];   // 4 slabs x 64 rows x 32 cols
    __shared__ ushort_t Bs[4 * 4096];   // 4 slabs x 128 rows x 32 cols
    const ushort_t* A  = wsb + CTX_OFF;
    const ushort_t* Bm = wsb + WO_OFF;
    const int bid = blockIdx.x;          // 0..511
    const int xs = bid & 7, t = bid >> 3;   // t 0..63
    const int m0 = (xs * 8 + (t & 7)) * 64; // 64 m-tiles, grouped per XCD
    const int n0 = (t >> 3) * 128;          // 8 n-tiles

    const int tid = threadIdx.x, wave = tid >> 6, lane = tid & 63;
    const int lane15 = lane & 15, quad = lane >> 4;
    const int rsw = ((quad ^ ((lane15 >> 1) & 3)) << 3);   // swizzled read chunk col

    f32x4 acc[8];
    #pragma unroll
    for (int j = 0; j < 8; ++j) acc[j] = (f32x4){0.f, 0.f, 0.f, 0.f};

    #pragma unroll 1
    for (int kt = 0; kt < 8; ++kt) {
        const int k0 = kt * 128;
        __syncthreads();
        #pragma unroll
        for (int s = 0; s < 4; ++s) {
            {
                int n = wave * 64 + lane;              // A chunk 0..255 (4 chunks/row)
                int row = n >> 2;
                int c = (n & 3) ^ ((row >> 1) & 3);    // swizzled src chunk
                load_lds16(A + (size_t)(m0 + row) * 1024 + k0 + s * 32 + c * 8,
                           As + s * 2048 + wave * 512);
            }
            #pragma unroll
            for (int m = 0; m < 2; ++m) {
                int n = m * 256 + wave * 64 + lane;    // B chunk 0..511
                int row = n >> 2;
                int c = (n & 3) ^ ((row >> 1) & 3);    // swizzled src chunk
                load_lds16(Bm + (size_t)(n0 + row) * 1024 + k0 + s * 32 + c * 8,
                           Bs + s * 4096 + (m * 256 + wave * 64) * 8);
            }
        }
        __syncthreads();

        #pragma unroll
        for (int s = 0; s < 4; ++s) {
            short8 a = *(const short8*)&As[s * 2048 + (wave * 16 + lane15) * 32 + rsw];
            #pragma unroll
            for (int j = 0; j < 8; ++j) {
                short8 bf = *(const short8*)&Bs[s * 4096 + (j * 16 + lane15) * 32 + rsw];
                acc[j] = __builtin_amdgcn_mfma_f32_16x16x32_bf16(a, bf, acc[j], 0, 0, 0);
            }
        }
    }

    #pragma unroll
    for (int j = 0; j < 8; ++j) {
        int col = n0 + j * 16 + lane15;
        float bv_ = bo[col];
        #pragma unroll
        for (int r = 0; r < 4; ++r) {
            int row = m0 + wave * 16 + quad * 4 + r;
            out[(size_t)row * EE + col] = acc[j][r] + bv_;
        }
    }
}

// ---------------------------------------------------------------------------
extern "C" void kernel_launch(void* const* d_in, const int* in_sizes, int n_in,
                              void* d_out, int out_size, void* d_ws, size_t ws_size,
                              hipStream_t stream) {
    const float* q    = (const float*)d_in[0];
    const float* k    = (const float*)d_in[1];
    const float* v    = (const float*)d_in[2];
    const int*   mask = (const int*)  d_in[3];
    const float* Wq   = (const float*)d_in[4];
    const float* bq   = (const float*)d_in[5];
    const float* Wk   = (const float*)d_in[6];
    const float* bk   = (const float*)d_in[7];
    const float* Wv   = (const float*)d_in[8];
    const float* bv   = (const float*)d_in[9];
    const float* Wo   = (const float*)d_in[10];
    const float* bo   = (const float*)d_in[11];

    ushort_t* wsb = (ushort_t*)d_ws;
    unsigned* maskbits = (unsigned*)(wsb + MB_OFF);

    prep_kernel<<<20480, 256, 0, stream>>>(q, k, v, mask, Wq, Wk, Wv, Wo, wsb, maskbits);
    gemm_qkv<<<dim3(8, 32, 3), 256, 0, stream>>>(wsb, bq, bk, bv);
    attn_kernel<<<512, 256, 0, stream>>>(wsb, maskbits, wsb + CTX_OFF);
    gemm_out<<<512, 256, 0, stream>>>(wsb, bo, (float*)d_out);
}